// Round 3
// baseline (791.351 us; speedup 1.0000x reference)
//
#include <hip/hip_runtime.h>
#include <hip/hip_bf16.h>
#include <math.h>

// Problem constants
#define T_TOKENS 16384
#define HID      2048
#define NE       64     // experts
#define TOPK     8
// Tiling
#define TM       32     // tokens per block  -> grid 512 = 2 blocks/CU
#define BK       64     // k-chunk
#define STR      (BK + 1)  // LDS row stride 65: row->bank step 1, conflict-free

__global__ __launch_bounds__(256, 2) void router_kernel(
    const float* __restrict__ hidden,   // [T_TOKENS, HID]
    const float* __restrict__ weight,   // [NE, HID]
    float* __restrict__ out_logits,     // [T_TOKENS, NE]
    float* __restrict__ out_vals,       // [T_TOKENS, TOPK]
    float* __restrict__ out_idxf)       // [T_TOKENS, TOPK] (indices stored as float)
{
    // Staging: hs_s[32][65] f32 (8320 B) + w_s[64][65] f32 (16640 B) = 24960 B.
    // Epilogue aliases an f64 logit tile lg[32][65] (16640 B) over the same LDS.
    __shared__ __align__(16) char smem[TM * STR * 4 + NE * STR * 4];
    float (*hs_s)[STR] = reinterpret_cast<float(*)[STR]>(smem);
    float (*w_s)[STR]  = reinterpret_cast<float(*)[STR]>(smem + TM * STR * 4);
    double (*lg)[STR]  = reinterpret_cast<double(*)[STR]>(smem);

    const int tid  = threadIdx.x;
    const int tok0 = blockIdx.x * TM;

    // Thread tile: 4 tokens x 2 experts. Wave layout: ty in {w*2, w*2+1} (A reads
    // are 32-lane broadcasts), tx = 0..31 (B reads tile all 32 banks densely).
    const int ty = tid >> 5;   // 0..7  token group (4 tokens each)
    const int tx = tid & 31;   // 0..31 expert group (2 experts each)

    // fp64 accumulation: exact-enough ranking vs numpy ref (f32 seq error
    // ~2e-6 flips ranks at the top-8 boundary; f64 error ~1e-16 never does).
    double acc[4][2];
    #pragma unroll
    for (int i = 0; i < 4; ++i) { acc[i][0] = 0.0; acc[i][1] = 0.0; }

    const int srow = tid >> 4;         // 0..15
    const int scol = (tid & 15) << 2;  // 0..60 step 4

    for (int k0 = 0; k0 < HID; k0 += BK) {
        // ---- stage hidden tile [TM][BK] and weight tile [NE][BK] (f32) ----
        #pragma unroll
        for (int r = 0; r < 2; ++r) {
            const int rr = srow + r * 16;  // 0..31
            *(float4*)&hs_s[rr][scol] =
                *(const float4*)&hidden[(size_t)(tok0 + rr) * HID + k0 + scol];
        }
        #pragma unroll
        for (int r = 0; r < 4; ++r) {
            const int rr = srow + r * 16;  // 0..63
            *(float4*)&w_s[rr][scol] =
                *(const float4*)&weight[(size_t)rr * HID + k0 + scol];
        }
        __syncthreads();

        // ---- compute: 4 tokens x 2 experts per thread, f64 accumulate ----
        #pragma unroll 4
        for (int kk = 0; kk < BK; kk += 4) {
            float4 af[4], bf[2];
            #pragma unroll
            for (int i = 0; i < 4; ++i) af[i] = *(const float4*)&hs_s[ty * 4 + i][kk];
            #pragma unroll
            for (int j = 0; j < 2; ++j) bf[j] = *(const float4*)&w_s[tx * 2 + j][kk];
            double a[4][4], b[2][4];
            #pragma unroll
            for (int i = 0; i < 4; ++i) {
                a[i][0] = (double)af[i].x; a[i][1] = (double)af[i].y;
                a[i][2] = (double)af[i].z; a[i][3] = (double)af[i].w;
            }
            #pragma unroll
            for (int j = 0; j < 2; ++j) {
                b[j][0] = (double)bf[j].x; b[j][1] = (double)bf[j].y;
                b[j][2] = (double)bf[j].z; b[j][3] = (double)bf[j].w;
            }
            #pragma unroll
            for (int i = 0; i < 4; ++i)
                #pragma unroll
                for (int j = 0; j < 2; ++j) {
                    acc[i][j] = fma(a[i][0], b[j][0], acc[i][j]);
                    acc[i][j] = fma(a[i][1], b[j][1], acc[i][j]);
                    acc[i][j] = fma(a[i][2], b[j][2], acc[i][j]);
                    acc[i][j] = fma(a[i][3], b[j][3], acc[i][j]);
                }
        }
        __syncthreads();
    }

    // ---- write logits to global (coalesced float2, rounded from f64) ----
    #pragma unroll
    for (int i = 0; i < 4; ++i) {
        const int tok = tok0 + ty * 4 + i;
        float2 v = make_float2((float)acc[i][0], (float)acc[i][1]);
        *(float2*)&out_logits[(size_t)tok * NE + tx * 2] = v;
    }

    // ---- stash f64 logit tile in LDS (aliases staging bufs; K-loop ended
    //      with __syncthreads so all compute reads are done) ----
    #pragma unroll
    for (int i = 0; i < 4; ++i) {
        lg[ty * 4 + i][tx * 2 + 0] = acc[i][0];
        lg[ty * 4 + i][tx * 2 + 1] = acc[i][1];
    }
    __syncthreads();

    // ---- per-token top-8 + renormalized softmax over the selected 8 ----
    // Full softmax denominator cancels under renorm: vals = exp(l - lmax) / sum_top8.
    const int wave = tid >> 6;   // 0..3
    const int lane = tid & 63;   // expert id for this lane

    for (int tt = wave; tt < TM; tt += 4) {
        double cur = lg[tt][lane];
        double first = 0.0, s = 0.0, myv = 0.0;
        int myi = 0;
        #pragma unroll
        for (int i = 0; i < TOPK; ++i) {
            double mv = cur;
            int    mi = lane;
            #pragma unroll
            for (int off = 32; off; off >>= 1) {
                const double ov = __shfl_xor(mv, off);
                const int    oi = __shfl_xor(mi, off);
                if (ov > mv || (ov == mv && oi < mi)) { mv = ov; mi = oi; }
            }
            if (i == 0) first = mv;
            const double e = exp(mv - first);
            s += e;
            if (lane == i)  { myv = e; myi = mi; }
            if (lane == mi) cur = -INFINITY;   // remove winner
        }
        if (lane < TOPK) {
            const int tok = tok0 + tt;
            out_vals[(size_t)tok * TOPK + lane] = (float)(myv / s);
            out_idxf[(size_t)tok * TOPK + lane] = (float)myi;
        }
    }
}

extern "C" void kernel_launch(void* const* d_in, const int* in_sizes, int n_in,
                              void* d_out, int out_size, void* d_ws, size_t ws_size,
                              hipStream_t stream) {
    const float* hidden = (const float*)d_in[0];   // [16384, 2048] f32
    const float* weight = (const float*)d_in[1];   // [64, 2048] f32

    float* out        = (float*)d_out;
    float* out_logits = out;                                    // 16384*64
    float* out_vals   = out + (size_t)T_TOKENS * NE;            // 16384*8
    float* out_idxf   = out + (size_t)T_TOKENS * NE
                            + (size_t)T_TOKENS * TOPK;          // 16384*8

    dim3 grid(T_TOKENS / TM);
    dim3 block(256);
    hipLaunchKernelGGL(router_kernel, grid, block, 0, stream,
                       hidden, weight, out_logits, out_vals, out_idxf);
}

// Round 4
// 361.583 us; speedup vs baseline: 2.1886x; 2.1886x over previous
//
#include <hip/hip_runtime.h>
#include <hip/hip_bf16.h>
#include <math.h>

// Problem constants
#define T_TOKENS 16384
#define HID      2048
#define NE       64     // experts
#define TOPK     8
// Tiling
#define TM       32     // tokens per block -> grid 512 = 2 blocks/CU, 8 waves/CU
#define BK       64     // k-chunk
#define ASTR     66     // A LDS row stride in f64: 528 B = 16B-aligned, rows hit
                        // different banks (132 dwords ≡ 4 mod 32)
#define BSTR     66     // B K-major row stride in f64 (row = one k, 64 experts)

__global__ __launch_bounds__(256, 2) void router_kernel(
    const float* __restrict__ hidden,   // [T_TOKENS, HID]
    const float* __restrict__ weight,   // [NE, HID]
    float* __restrict__ out_logits,     // [T_TOKENS, NE]
    float* __restrict__ out_vals,       // [T_TOKENS, TOPK]
    float* __restrict__ out_idxf)       // [T_TOKENS, TOPK] (indices stored as float)
{
    // aS: [TM][ASTR] f64 row-major (tokens)      = 16896 B
    // bS: [BK][BSTR] f64 K-major (k rows)        = 33792 B   total 50688 B
    // Epilogue aliases lg[TM][65] f64 (16640 B) over the front.
    __shared__ __align__(16) char smem[(TM * ASTR + BK * BSTR) * 8];
    double (*aS)[ASTR] = reinterpret_cast<double(*)[ASTR]>(smem);
    double (*bS)[BSTR] = reinterpret_cast<double(*)[BSTR]>(smem + TM * ASTR * 8);
    double (*lg)[65]   = reinterpret_cast<double(*)[65]>(smem);

    const int tid  = threadIdx.x;
    const int tok0 = blockIdx.x * TM;

    // Compute mapping: 4 tokens x 2 experts per thread.
    // Within a wave: ty in {0,1} -> A reads are 2-address near-broadcast (free);
    // tx = 0..31 -> B double2 reads at [k][2tx] tile all 32 banks, conflict-free,
    // 16B-aligned, compile-time k offsets (K-major layout, no swizzle needed).
    const int ty = tid >> 5;   // 0..7  token group (4 tokens each)
    const int tx = tid & 31;   // 0..31 expert pair

    // f64 accumulation: exact-enough ranking vs the numpy reference (f32 seq
    // error ~2e-6 flips top-8 ranks; f64 never does). All cvt f32->f64 happen
    // at staging (once per element) so the K-loop is pure v_fma_f64.
    double acc[4][2];
    #pragma unroll
    for (int i = 0; i < 4; ++i) { acc[i][0] = 0.0; acc[i][1] = 0.0; }

    // Staging maps
    const int ar  = tid >> 3;          // 0..31  A row (token)
    const int ac8 = (tid & 7) * 8;     // 0..56  A col start (8 k's per thread)
    const int be  = tid >> 2;          // 0..63  B row (expert)
    const int bk16 = (tid & 3) * 16;   // 0..48  B col start (16 k's per thread)

    for (int k0 = 0; k0 < HID; k0 += BK) {
        // ---- stage A tile [TM][BK] as f64, row-major ----
        {
            const float4 v0 = *(const float4*)&hidden[(size_t)(tok0 + ar) * HID + k0 + ac8];
            const float4 v1 = *(const float4*)&hidden[(size_t)(tok0 + ar) * HID + k0 + ac8 + 4];
            *(double2*)&aS[ar][ac8 + 0] = double2{(double)v0.x, (double)v0.y};
            *(double2*)&aS[ar][ac8 + 2] = double2{(double)v0.z, (double)v0.w};
            *(double2*)&aS[ar][ac8 + 4] = double2{(double)v1.x, (double)v1.y};
            *(double2*)&aS[ar][ac8 + 6] = double2{(double)v1.z, (double)v1.w};
        }
        // ---- stage B tile [NE][BK] as f64, K-major (transpose in-flight) ----
        #pragma unroll
        for (int q = 0; q < 4; ++q) {
            const float4 w = *(const float4*)&weight[(size_t)be * HID + k0 + bk16 + 4 * q];
            bS[bk16 + 4 * q + 0][be] = (double)w.x;
            bS[bk16 + 4 * q + 1][be] = (double)w.y;
            bS[bk16 + 4 * q + 2][be] = (double)w.z;
            bS[bk16 + 4 * q + 3][be] = (double)w.w;
        }
        __syncthreads();

        // ---- compute: pure f64 FMA; 2 k's per step ----
        #pragma unroll 4
        for (int c = 0; c < BK / 2; ++c) {
            const double2 b0 = *(const double2*)&bS[2 * c + 0][2 * tx]; // experts 2tx,2tx+1 @ k=2c
            const double2 b1 = *(const double2*)&bS[2 * c + 1][2 * tx]; // @ k=2c+1
            #pragma unroll
            for (int i = 0; i < 4; ++i) {
                const double2 a = *(const double2*)&aS[ty * 4 + i][2 * c]; // k pair
                acc[i][0] = fma(a.y, b1.x, fma(a.x, b0.x, acc[i][0]));
                acc[i][1] = fma(a.y, b1.y, fma(a.x, b0.y, acc[i][1]));
            }
        }
        __syncthreads();
    }

    // ---- write logits to global (coalesced float2, rounded from f64) ----
    #pragma unroll
    for (int i = 0; i < 4; ++i) {
        const int tok = tok0 + ty * 4 + i;
        float2 v = make_float2((float)acc[i][0], (float)acc[i][1]);
        *(float2*)&out_logits[(size_t)tok * NE + tx * 2] = v;
    }

    // ---- stash f64 logit tile in LDS (aliases staging bufs; K-loop ended
    //      with __syncthreads so all compute reads are done) ----
    #pragma unroll
    for (int i = 0; i < 4; ++i) {
        lg[ty * 4 + i][tx * 2 + 0] = acc[i][0];
        lg[ty * 4 + i][tx * 2 + 1] = acc[i][1];
    }
    __syncthreads();

    // ---- per-token top-8 + renormalized softmax over the selected 8 ----
    // Full softmax denominator cancels under renorm: vals = exp(l - lmax) / sum_top8.
    const int wave = tid >> 6;   // 0..3
    const int lane = tid & 63;   // expert id for this lane

    for (int tt = wave; tt < TM; tt += 4) {
        double cur = lg[tt][lane];
        double first = 0.0, s = 0.0, myv = 0.0;
        int myi = 0;
        #pragma unroll
        for (int i = 0; i < TOPK; ++i) {
            double mv = cur;
            int    mi = lane;
            #pragma unroll
            for (int off = 32; off; off >>= 1) {
                const double ov = __shfl_xor(mv, off);
                const int    oi = __shfl_xor(mi, off);
                if (ov > mv || (ov == mv && oi < mi)) { mv = ov; mi = oi; }
            }
            if (i == 0) first = mv;
            const double e = exp(mv - first);
            s += e;
            if (lane == i)  { myv = e; myi = mi; }
            if (lane == mi) cur = -INFINITY;   // remove winner
        }
        if (lane < TOPK) {
            const int tok = tok0 + tt;
            out_vals[(size_t)tok * TOPK + lane] = (float)(myv / s);
            out_idxf[(size_t)tok * TOPK + lane] = (float)myi;
        }
    }
}

extern "C" void kernel_launch(void* const* d_in, const int* in_sizes, int n_in,
                              void* d_out, int out_size, void* d_ws, size_t ws_size,
                              hipStream_t stream) {
    const float* hidden = (const float*)d_in[0];   // [16384, 2048] f32
    const float* weight = (const float*)d_in[1];   // [64, 2048] f32

    float* out        = (float*)d_out;
    float* out_logits = out;                                    // 16384*64
    float* out_vals   = out + (size_t)T_TOKENS * NE;            // 16384*8
    float* out_idxf   = out + (size_t)T_TOKENS * NE
                            + (size_t)T_TOKENS * TOPK;          // 16384*8

    dim3 grid(T_TOKENS / TM);
    dim3 block(256);
    hipLaunchKernelGGL(router_kernel, grid, block, 0, stream,
                       hidden, weight, out_logits, out_vals, out_idxf);
}